// Round 14
// baseline (236.224 us; speedup 1.0000x reference)
//
#include <hip/hip_runtime.h>

typedef __attribute__((ext_vector_type(8))) __bf16 bf16x8;
typedef __attribute__((ext_vector_type(4))) float f32x4;

#define EXP2 __builtin_amdgcn_exp2f
#define LOG2E 1.44269504f
#define MFMA __builtin_amdgcn_mfma_f32_16x16x32_bf16

// async global->LDS 16B per lane: dst wave-uniform, src per-lane (+lane*16B)
#define GLL(srcp, dstp) __builtin_amdgcn_global_load_lds( \
    (const __attribute__((address_space(1))) void*)(srcp), \
    (__attribute__((address_space(3))) void*)(dstp), 16, 0, 0)

__device__ __forceinline__ float lrelu(float v, float s) { return v > 0.f ? v : v * s; }

__device__ __forceinline__ unsigned short f2bf(float f) {
    unsigned int u = __float_as_uint(f);
    u += 0x7FFFu + ((u >> 16) & 1u);
    return (unsigned short)(u >> 16);
}
__device__ __forceinline__ float bf2f(unsigned short u) {
    return __uint_as_float((unsigned int)u << 16);
}

__device__ __forceinline__ int ld_idx(const int* p, int e, int is64) {
    return is64 ? (int)(((const long long*)p)[e]) : p[e];
}

__global__ void detect_i64(const unsigned int* idx, int* flag) {
    if (blockIdx.x == 0 && threadIdx.x == 0) {
        int all0 = 1;
        for (int i = 1; i < 256; i += 2) {
            if (idx[i] != 0u) { all0 = 0; break; }
        }
        *flag = all0;
    }
}

// ---------------- fused conversions (fragment-linear layouts) ----------------
__global__ void convert_all(const float* __restrict__ x,
                            const float* __restrict__ W1l, const float* __restrict__ W1r,
                            const float* __restrict__ W2l, const float* __restrict__ W2r,
                            unsigned short* __restrict__ xb,
                            unsigned short* __restrict__ w1t, unsigned short* __restrict__ w2t,
                            int n, int nrb)
{
    int t = blockIdx.x * blockDim.x + threadIdx.x;
    int A = nrb * 512;
    if (t < A) {
        int lane = t & 63;
        int kf = (t >> 6) & 7;
        int rowblk = t >> 9;
        int r16 = lane & 15, kg = lane >> 4;
        int row = rowblk * 16 + r16;
        int k0 = kf * 32 + kg * 8;
        ushort4 o0 = {0, 0, 0, 0}, o1 = {0, 0, 0, 0};
        if (row < n) {
            float4 v0 = *(const float4*)(x + (size_t)row * 256 + k0);
            float4 v1 = *(const float4*)(x + (size_t)row * 256 + k0 + 4);
            o0.x = f2bf(v0.x); o0.y = f2bf(v0.y); o0.z = f2bf(v0.z); o0.w = f2bf(v0.w);
            o1.x = f2bf(v1.x); o1.y = f2bf(v1.y); o1.z = f2bf(v1.z); o1.w = f2bf(v1.w);
        }
        *(ushort4*)(xb + (size_t)t * 8) = o0;
        *(ushort4*)(xb + (size_t)t * 8 + 4) = o1;
        return;
    }
    int tw = t - A;
    const float *Wl, *Wr;
    unsigned short* dst;
    int NL, base;
    if (tw < 16384)      { Wl = W1l; Wr = W1r; dst = w1t; NL = 256; base = tw; }
    else if (tw < 20480) { Wl = W2l; Wr = W2r; dst = w2t; NL = 64;  base = tw - 16384; }
    else return;
    int lane = base & 63, kf = (base >> 6) & 7, colblk = base >> 9;
    int r16 = lane & 15, kg = lane >> 4;
    int col = colblk * 16 + r16;
    int k0 = kf * 32 + kg * 8;
    const float* W = (col < NL) ? Wl : Wr;
    int c = (col < NL) ? col : col - NL;
    unsigned short v[8];
#pragma unroll
    for (int e = 0; e < 8; e++) v[e] = f2bf(W[(size_t)(k0 + e) * NL + c]);
    ushort4 o0 = {v[0], v[1], v[2], v[3]}, o1 = {v[4], v[5], v[6], v[7]};
    *(ushort4*)(dst + (size_t)base * 8) = o0;
    *(ushort4*)(dst + (size_t)base * 8 + 4) = o1;
}

// ---------------- LDS-staged double-buffered MFMA GEMM ----------------
template <int KF>
__global__ __launch_bounds__(256) void gemm_lds(
    const unsigned short* __restrict__ A, const unsigned short* __restrict__ Bt,
    const float* __restrict__ biasL, const float* __restrict__ biasR, int NL,
    unsigned short* __restrict__ C, int M, int nrb, int N)
{
    __shared__ unsigned short lds[2][16 * 512];   // 2 x 16KB
    int wid = threadIdx.x >> 6, lane = threadIdx.x & 63;
    int wm = wid >> 1, wn = wid & 1;
    int rb0 = blockIdx.x * 8;
    int cb0 = blockIdx.y * 8;

    auto stage = [&](int buf, int kf) {
#pragma unroll
        for (int i = 0; i < 4; i++) {
            int c = wid * 4 + i;
            const unsigned short* src;
            if (c < 8) {
                int rb = rb0 + c;
                rb = rb < nrb ? rb : nrb - 1;
                src = A + ((size_t)rb * KF + kf) * 512;
            } else {
                src = Bt + ((size_t)(cb0 + c - 8) * KF + kf) * 512;
            }
            GLL(src + lane * 8, &lds[buf][c * 512]);
        }
    };

    f32x4 acc[4][4] = {};
    stage(0, 0);
    __syncthreads();
    int cur = 0;
    for (int kf = 0; kf < KF; kf++) {
        if (kf + 1 < KF) stage(cur ^ 1, kf + 1);
        bf16x8 a[4], b[4];
#pragma unroll
        for (int r = 0; r < 4; r++)
            a[r] = *(const bf16x8*)&lds[cur][(wm * 4 + r) * 512 + lane * 8];
#pragma unroll
        for (int j = 0; j < 4; j++)
            b[j] = *(const bf16x8*)&lds[cur][(8 + wn * 4 + j) * 512 + lane * 8];
#pragma unroll
        for (int j = 0; j < 4; j++)
#pragma unroll
            for (int r = 0; r < 4; r++)
                acc[r][j] = MFMA(a[r], b[j], acc[r][j], 0, 0, 0);
        __syncthreads();
        cur ^= 1;
    }

    int ccol = lane & 15, crow = (lane >> 4) * 4;
#pragma unroll
    for (int r = 0; r < 4; r++) {
#pragma unroll
        for (int j = 0; j < 4; j++) {
            int col = (cb0 + wn * 4 + j) * 16 + ccol;
            float bv = (col < NL) ? biasL[col] : biasR[col - NL];
#pragma unroll
            for (int q = 0; q < 4; q++) {
                int row = (rb0 + wm * 4 + r) * 16 + crow + q;
                if (row < M) C[(size_t)row * N + col] = f2bf(acc[r][j][q] + bv);
            }
        }
    }
}

// ---------------- CSR build (single atomic pass) ----------------
__global__ void hist_dst_pos(const int* __restrict__ eidx, const int* __restrict__ flagp,
                             int E, int n, int* __restrict__ cnt, int* __restrict__ pos)
{
    int t = blockIdx.x * blockDim.x + threadIdx.x;
    if (t >= E + n) return;
    int is64 = *flagp;
    int d = (t < E) ? ld_idx(eidx, E + t, is64) : (t - E);
    pos[t] = atomicAdd(&cnt[d], 1);
}

__global__ __launch_bounds__(1024) void scan1(const int* __restrict__ cnt,
                                              int* __restrict__ rowptr, int* __restrict__ psum, int n)
{
    __shared__ int wsum[16];
    int tid = threadIdx.x, lane = tid & 63, w = tid >> 6;
    int gid = blockIdx.x * 1024 + tid;
    int v = (gid < n) ? cnt[gid] : 0;
    int sc = v;
#pragma unroll
    for (int o = 1; o < 64; o <<= 1) { int t2 = __shfl_up(sc, o); if (lane >= o) sc += t2; }
    if (lane == 63) wsum[w] = sc;
    __syncthreads();
    if (tid < 16) {
        int t2 = wsum[tid];
#pragma unroll
        for (int o = 1; o < 16; o <<= 1) { int u = __shfl_up(t2, o); if (tid >= o) t2 += u; }
        wsum[tid] = t2;
    }
    __syncthreads();
    int wofs = w ? wsum[w - 1] : 0;
    if (gid < n) rowptr[gid] = wofs + sc - v;
    if (tid == 1023) psum[blockIdx.x] = wsum[15];
}

__global__ void scan2(const int* __restrict__ psum, int* __restrict__ pofs,
                      int* __restrict__ rowptr_n, int nb)
{
    int lane = threadIdx.x;
    int v = (lane < nb) ? psum[lane] : 0;
    int sc = v;
#pragma unroll
    for (int o = 1; o < 64; o <<= 1) { int t = __shfl_up(sc, o); if (lane >= o) sc += t; }
    if (lane < nb) pofs[lane] = sc - v;
    if (lane == 63) *rowptr_n = sc;
}

__global__ __launch_bounds__(1024) void scan3(int* __restrict__ rowptr,
                                              const int* __restrict__ pofs, int n)
{
    int gid = blockIdx.x * 1024 + threadIdx.x;
    if (gid < n) rowptr[gid] += pofs[blockIdx.x];
}

__global__ void scatter_pos(const int* __restrict__ eidx, const int* __restrict__ flagp,
                            int E, int n, const int* __restrict__ rowptr,
                            const int* __restrict__ pos, int* __restrict__ sord)
{
    int t = blockIdx.x * blockDim.x + threadIdx.x;
    if (t >= E + n) return;
    int is64 = *flagp;
    int s, d;
    if (t < E) { s = ld_idx(eidx, t, is64); d = ld_idx(eidx, E + t, is64); }
    else { s = t - E; d = s; }
    sord[rowptr[d] + pos[t]] = s;
}

// ---------------- fused edge phase, H=4: one WAVE per node, 8ch/lane, 2 edges/step ----
// lane: slot = lane>>5 (edge), sub = lane&31, channel base off = sub*8 (covers 256 ch).
// no-max softmax (shift-invariant); score folds LOG2E+lrelu split into a6/a4.
__global__ __launch_bounds__(64) void node_attn_h4(
    const unsigned short* __restrict__ xlr,  // [n][512]: 0-255 xl, 256-511 xr
    const float* __restrict__ att, const float* __restrict__ bias,
    const int* __restrict__ rowptr, const int* __restrict__ sord, int n,
    unsigned short* __restrict__ outb)       // frag layout (feeds gemm2)
{
    int d = blockIdx.x;
    int lane = threadIdx.x;
    int slot = lane >> 5, sub = lane & 31;
    int off = sub * 8;
    float xr8[8], a68[8], a48[8];
    {
        ushort4 u0 = *(const ushort4*)(xlr + (size_t)d * 512 + 256 + off);
        ushort4 u1 = *(const ushort4*)(xlr + (size_t)d * 512 + 256 + off + 4);
        xr8[0] = bf2f(u0.x); xr8[1] = bf2f(u0.y); xr8[2] = bf2f(u0.z); xr8[3] = bf2f(u0.w);
        xr8[4] = bf2f(u1.x); xr8[5] = bf2f(u1.y); xr8[6] = bf2f(u1.z); xr8[7] = bf2f(u1.w);
        float4 av0 = *(const float4*)(att + off);
        float4 av1 = *(const float4*)(att + off + 4);
        float av[8] = {av0.x, av0.y, av0.z, av0.w, av1.x, av1.y, av1.z, av1.w};
#pragma unroll
        for (int c = 0; c < 8; c++) {
            a68[c] = av[c] * (0.6f * LOG2E);
            a48[c] = av[c] * (0.4f * LOG2E);
        }
    }
    int beg = rowptr[d], end = rowptr[d + 1];
    float ssum = 0.f;
    float o8[8] = {};
    for (int i = beg; i < end; i += 2) {
        int ia = i + slot;
        int va = ia < end;
        int sa = sord[va ? ia : i];
        const unsigned short* rp = xlr + (size_t)sa * 512 + off;
        ushort4 u0 = *(const ushort4*)rp;
        ushort4 u1 = *(const ushort4*)(rp + 4);
        float x8[8];
        x8[0] = bf2f(u0.x); x8[1] = bf2f(u0.y); x8[2] = bf2f(u0.z); x8[3] = bf2f(u0.w);
        x8[4] = bf2f(u1.x); x8[5] = bf2f(u1.y); x8[6] = bf2f(u1.z); x8[7] = bf2f(u1.w);
        float p = 0.f;
#pragma unroll
        for (int c = 0; c < 8; c++) {
            float t_ = x8[c] + xr8[c];
            p = fmaf(t_, a68[c], p);
            p = fmaf(fabsf(t_), a48[c], p);
        }
        p += __shfl_xor(p, 1);
        p += __shfl_xor(p, 2);
        p += __shfl_xor(p, 4);   // p uniform within 8-lane head group
        p = va ? p : -1e30f;
        float ev = EXP2(p);
        ssum += ev;
#pragma unroll
        for (int c = 0; c < 8; c++) o8[c] = fmaf(ev, x8[c], o8[c]);
    }
    // merge the 2 edge slots
    ssum += __shfl_xor(ssum, 32);
#pragma unroll
    for (int c = 0; c < 8; c++) o8[c] += __shfl_xor(o8[c], 32);
    if (slot == 0) {
        float inv = 1.f / (ssum + 1e-16f);
        float4 bv0 = *(const float4*)(bias + off);
        float4 bv1 = *(const float4*)(bias + off + 4);
        float bv[8] = {bv0.x, bv0.y, bv0.z, bv0.w, bv1.x, bv1.y, bv1.z, bv1.w};
        unsigned short r[8];
#pragma unroll
        for (int c = 0; c < 8; c++) {
            float v = o8[c] * inv + bv[c];
            v = fmaxf(v, 0.01f * v);
            r[c] = f2bf(v);
        }
        // frag store: row=d, channels off..off+7 = one full 8-elem chunk slot
        int rowblk = d >> 4, r16d = d & 15;
        int kf = off >> 5, kg = (off >> 3) & 3;
        size_t flat = (((size_t)rowblk * 8 + kf) * 64 + kg * 16 + r16d) * 8;
        ushort4 q0 = {r[0], r[1], r[2], r[3]}, q1 = {r[4], r[5], r[6], r[7]};
        *(ushort4*)(outb + flat) = q0;
        *(ushort4*)(outb + flat + 4) = q1;
    }
}

// ---------------- fused edge phase, H=1: one WAVE per node, 8ch/lane, 8 edges/step ----
__global__ __launch_bounds__(64) void node_attn_h1(
    const unsigned short* __restrict__ xlr,  // [n][128]: 0-63 xl, 64-127 xr
    const float* __restrict__ att, const float* __restrict__ bias,
    const int* __restrict__ rowptr, const int* __restrict__ sord, int n,
    float* __restrict__ outf)
{
    int d = blockIdx.x;
    int lane = threadIdx.x;
    int slot = lane >> 3, sub = lane & 7;
    int off = sub * 8;
    float xr8[8], a68[8], a48[8];
    {
        ushort4 u0 = *(const ushort4*)(xlr + (size_t)d * 128 + 64 + off);
        ushort4 u1 = *(const ushort4*)(xlr + (size_t)d * 128 + 64 + off + 4);
        xr8[0] = bf2f(u0.x); xr8[1] = bf2f(u0.y); xr8[2] = bf2f(u0.z); xr8[3] = bf2f(u0.w);
        xr8[4] = bf2f(u1.x); xr8[5] = bf2f(u1.y); xr8[6] = bf2f(u1.z); xr8[7] = bf2f(u1.w);
        float4 av0 = *(const float4*)(att + off);
        float4 av1 = *(const float4*)(att + off + 4);
        float av[8] = {av0.x, av0.y, av0.z, av0.w, av1.x, av1.y, av1.z, av1.w};
#pragma unroll
        for (int c = 0; c < 8; c++) {
            a68[c] = av[c] * (0.6f * LOG2E);
            a48[c] = av[c] * (0.4f * LOG2E);
        }
    }
    int beg = rowptr[d], end = rowptr[d + 1];
    float ssum = 0.f;
    float o8[8] = {};
    for (int i = beg; i < end; i += 8) {
        int ia = i + slot;
        int va = ia < end;
        int sa = sord[va ? ia : i];
        const unsigned short* rp = xlr + (size_t)sa * 128 + off;
        ushort4 u0 = *(const ushort4*)rp;
        ushort4 u1 = *(const ushort4*)(rp + 4);
        float x8[8];
        x8[0] = bf2f(u0.x); x8[1] = bf2f(u0.y); x8[2] = bf2f(u0.z); x8[3] = bf2f(u0.w);
        x8[4] = bf2f(u1.x); x8[5] = bf2f(u1.y); x8[6] = bf2f(u1.z); x8[7] = bf2f(u1.w);
        float p = 0.f;
#pragma unroll
        for (int c = 0; c < 8; c++) {
            float t_ = x8[c] + xr8[c];
            p = fmaf(t_, a68[c], p);
            p = fmaf(fabsf(t_), a48[c], p);
        }
        p += __shfl_xor(p, 1);
        p += __shfl_xor(p, 2);
        p += __shfl_xor(p, 4);   // p uniform within 8-lane edge group
        p = va ? p : -1e30f;
        float ev = EXP2(p);
        ssum += ev;
#pragma unroll
        for (int c = 0; c < 8; c++) o8[c] = fmaf(ev, x8[c], o8[c]);
    }
    // merge the 8 edge slots
#pragma unroll
    for (int offs = 8; offs <= 32; offs <<= 1) {
        ssum += __shfl_xor(ssum, offs);
#pragma unroll
        for (int c = 0; c < 8; c++) o8[c] += __shfl_xor(o8[c], offs);
    }
    if (slot == 0) {
        float inv = 1.f / (ssum + 1e-16f);
        float4 bv0 = *(const float4*)(bias + off);
        float4 bv1 = *(const float4*)(bias + off + 4);
        float4 res0, res1;
        res0.x = o8[0] * inv + bv0.x; res0.y = o8[1] * inv + bv0.y;
        res0.z = o8[2] * inv + bv0.z; res0.w = o8[3] * inv + bv0.w;
        res1.x = o8[4] * inv + bv1.x; res1.y = o8[5] * inv + bv1.y;
        res1.z = o8[6] * inv + bv1.z; res1.w = o8[7] * inv + bv1.w;
        *(float4*)(outf + (size_t)d * 64 + off) = res0;
        *(float4*)(outf + (size_t)d * 64 + off + 4) = res1;
    }
}

// fused predict head
__global__ void predict_head(const float* __restrict__ h2,
                             const float* __restrict__ Wp1, const float* __restrict__ bp1,
                             const float* __restrict__ Wp2, const float* __restrict__ bp2,
                             float* __restrict__ logits, int n)
{
    int i = blockIdx.x * blockDim.x + threadIdx.x;
    if (i >= n) return;
    float h[64];
#pragma unroll
    for (int c = 0; c < 64; c++) h[c] = h2[(long long)i * 64 + c];
    float logit = bp2[0];
#pragma unroll
    for (int j = 0; j < 32; j++) {
        float z = bp1[j];
#pragma unroll
        for (int c = 0; c < 64; c++) z += h[c] * Wp1[c * 32 + j];
        z = lrelu(z, 0.01f);
        logit += z * Wp2[j];
    }
    logits[i] = logit;
}

extern "C" void kernel_launch(void* const* d_in, const int* in_sizes, int n_in,
                              void* d_out, int out_size, void* d_ws, size_t ws_size,
                              hipStream_t stream)
{
    const float* x    = (const float*)d_in[0];
    const int*   eidx = (const int*)d_in[1];
    const float* W1l  = (const float*)d_in[2];
    const float* b1l  = (const float*)d_in[3];
    const float* W1r  = (const float*)d_in[4];
    const float* b1r  = (const float*)d_in[5];
    const float* att1 = (const float*)d_in[6];
    const float* bias1= (const float*)d_in[7];
    const float* W2l  = (const float*)d_in[8];
    const float* b2l  = (const float*)d_in[9];
    const float* W2r  = (const float*)d_in[10];
    const float* b2r  = (const float*)d_in[11];
    const float* att2 = (const float*)d_in[12];
    const float* bias2= (const float*)d_in[13];
    const float* Wp1  = (const float*)d_in[14];
    const float* bp1  = (const float*)d_in[15];
    const float* Wp2  = (const float*)d_in[16];
    const float* bp2  = (const float*)d_in[17];

    const int n = in_sizes[0] / 256;  // 50000
    const int E = in_sizes[1] / 2;    // 600000
    const int Etot = E + n;
    const int nb = (n + 1023) / 1024;
    const int nrb = (n + 15) / 16;    // 16-row blocks

    float* out = (float*)d_out;       // [0,n): logits ; [n, n+n*64): h
    unsigned short* ws16 = (unsigned short*)d_ws;

    // workspace layout (shorts)
    unsigned short* xb    = ws16;                         // nrb*4096 (frag; aliased h1b)
    unsigned short* xlr1  = xb + (size_t)nrb * 4096;      // n*512 row-major (aliased xlr2)
    unsigned short* w1t   = xlr1 + (size_t)n * 512;       // 131072 (frag)
    unsigned short* w2t   = w1t + 131072;                 // 32768 (frag)
    int*            rowptr= (int*)(w2t + 32768);          // n+1
    int*            cnt   = rowptr + (n + 1);             // n
    int*            sord  = cnt + n;                      // Etot
    int*            pos   = sord + Etot;                  // Etot
    int*            psum  = pos + Etot;                   // 64
    int*            pofs  = psum + 64;                    // 64
    int*            flagp = pofs + 64;                    // 1
    unsigned short* h1b   = xb;                           // attn1 out (frag), gemm2 in
    unsigned short* xlr2  = xlr1;                         // n*128 row-major
    float*          h2    = out + n;

    detect_i64<<<1, 64, 0, stream>>>((const unsigned int*)eidx, flagp);

    // ---- CSR build (one atomic pass) ----
    hipMemsetAsync(cnt, 0, (size_t)n * sizeof(int), stream);
    hist_dst_pos<<<(Etot + 255) / 256, 256, 0, stream>>>(eidx, flagp, E, n, cnt, pos);
    scan1<<<nb, 1024, 0, stream>>>(cnt, rowptr, psum, n);
    scan2<<<1, 64, 0, stream>>>(psum, pofs, rowptr + n, nb);
    scan3<<<nb, 1024, 0, stream>>>(rowptr, pofs, n);
    scatter_pos<<<(Etot + 255) / 256, 256, 0, stream>>>(eidx, flagp, E, n, rowptr, pos, sord);

    // ---- conversions (frag layouts, single launch) ----
    convert_all<<<(nrb * 512 + 20480 + 255) / 256, 256, 0, stream>>>(
        x, W1l, W1r, W2l, W2r, xb, w1t, w2t, n, nrb);

    // ---- layer 1 projection: [n,256] @ [512,256]^T, LDS-staged 128x128 tiles ----
    {
        dim3 grid((nrb + 7) / 8, 4);
        gemm_lds<8><<<grid, 256, 0, stream>>>(xb, w1t, b1l, b1r, 256, xlr1, n, nrb, 512);
    }

    // ---- layer 1 edge phase (one wave per node) ----
    node_attn_h4<<<n, 64, 0, stream>>>(xlr1, att1, bias1, rowptr, sord, n, h1b);

    // ---- layer 2 projection: [n,256] @ [128,256]^T ----
    {
        dim3 grid((nrb + 7) / 8, 1);
        gemm_lds<8><<<grid, 256, 0, stream>>>(h1b, w2t, b2l, b2r, 64, xlr2, n, nrb, 128);
    }

    // ---- layer 2 edge phase (one wave per node) ----
    node_attn_h1<<<n, 64, 0, stream>>>(xlr2, att2, bias2, rowptr, sord, n, h2);

    // ---- predict head ----
    predict_head<<<(n + 255) / 256, 256, 0, stream>>>(h2, Wp1, bp1, Wp2, bp2, out, n);
}

// Round 15
// 233.527 us; speedup vs baseline: 1.0116x; 1.0116x over previous
//
#include <hip/hip_runtime.h>

typedef __attribute__((ext_vector_type(8))) __bf16 bf16x8;
typedef __attribute__((ext_vector_type(4))) float f32x4;

#define EXP2 __builtin_amdgcn_exp2f
#define LOG2E 1.44269504f
#define MFMA __builtin_amdgcn_mfma_f32_16x16x32_bf16

// async global->LDS 16B per lane: dst wave-uniform, src per-lane (+lane*16B)
#define GLL(srcp, dstp) __builtin_amdgcn_global_load_lds( \
    (const __attribute__((address_space(1))) void*)(srcp), \
    (__attribute__((address_space(3))) void*)(dstp), 16, 0, 0)

__device__ __forceinline__ float lrelu(float v, float s) { return v > 0.f ? v : v * s; }

__device__ __forceinline__ unsigned short f2bf(float f) {
    unsigned int u = __float_as_uint(f);
    u += 0x7FFFu + ((u >> 16) & 1u);
    return (unsigned short)(u >> 16);
}
__device__ __forceinline__ float bf2f(unsigned short u) {
    return __uint_as_float((unsigned int)u << 16);
}

// unpack 8 bf16 (uint4) -> 8 floats: even = <<16, odd = &0xFFFF0000 (1 op each)
#define UNPK8(dst, u) { \
    dst[0] = __uint_as_float(u.x << 16); dst[1] = __uint_as_float(u.x & 0xFFFF0000u); \
    dst[2] = __uint_as_float(u.y << 16); dst[3] = __uint_as_float(u.y & 0xFFFF0000u); \
    dst[4] = __uint_as_float(u.z << 16); dst[5] = __uint_as_float(u.z & 0xFFFF0000u); \
    dst[6] = __uint_as_float(u.w << 16); dst[7] = __uint_as_float(u.w & 0xFFFF0000u); }

__device__ __forceinline__ int ld_idx(const int* p, int e, int is64) {
    return is64 ? (int)(((const long long*)p)[e]) : p[e];
}

__global__ void detect_i64(const unsigned int* idx, int* flag) {
    if (blockIdx.x == 0 && threadIdx.x == 0) {
        int all0 = 1;
        for (int i = 1; i < 256; i += 2) {
            if (idx[i] != 0u) { all0 = 0; break; }
        }
        *flag = all0;
    }
}

// ---------------- fused conversions (fragment-linear layouts) ----------------
__global__ void convert_all(const float* __restrict__ x,
                            const float* __restrict__ W1l, const float* __restrict__ W1r,
                            const float* __restrict__ W2l, const float* __restrict__ W2r,
                            unsigned short* __restrict__ xb,
                            unsigned short* __restrict__ w1t, unsigned short* __restrict__ w2t,
                            int n, int nrb)
{
    int t = blockIdx.x * blockDim.x + threadIdx.x;
    int A = nrb * 512;
    if (t < A) {
        int lane = t & 63;
        int kf = (t >> 6) & 7;
        int rowblk = t >> 9;
        int r16 = lane & 15, kg = lane >> 4;
        int row = rowblk * 16 + r16;
        int k0 = kf * 32 + kg * 8;
        ushort4 o0 = {0, 0, 0, 0}, o1 = {0, 0, 0, 0};
        if (row < n) {
            float4 v0 = *(const float4*)(x + (size_t)row * 256 + k0);
            float4 v1 = *(const float4*)(x + (size_t)row * 256 + k0 + 4);
            o0.x = f2bf(v0.x); o0.y = f2bf(v0.y); o0.z = f2bf(v0.z); o0.w = f2bf(v0.w);
            o1.x = f2bf(v1.x); o1.y = f2bf(v1.y); o1.z = f2bf(v1.z); o1.w = f2bf(v1.w);
        }
        *(ushort4*)(xb + (size_t)t * 8) = o0;
        *(ushort4*)(xb + (size_t)t * 8 + 4) = o1;
        return;
    }
    int tw = t - A;
    const float *Wl, *Wr;
    unsigned short* dst;
    int NL, base;
    if (tw < 16384)      { Wl = W1l; Wr = W1r; dst = w1t; NL = 256; base = tw; }
    else if (tw < 20480) { Wl = W2l; Wr = W2r; dst = w2t; NL = 64;  base = tw - 16384; }
    else return;
    int lane = base & 63, kf = (base >> 6) & 7, colblk = base >> 9;
    int r16 = lane & 15, kg = lane >> 4;
    int col = colblk * 16 + r16;
    int k0 = kf * 32 + kg * 8;
    const float* W = (col < NL) ? Wl : Wr;
    int c = (col < NL) ? col : col - NL;
    unsigned short v[8];
#pragma unroll
    for (int e = 0; e < 8; e++) v[e] = f2bf(W[(size_t)(k0 + e) * NL + c]);
    ushort4 o0 = {v[0], v[1], v[2], v[3]}, o1 = {v[4], v[5], v[6], v[7]};
    *(ushort4*)(dst + (size_t)base * 8) = o0;
    *(ushort4*)(dst + (size_t)base * 8 + 4) = o1;
}

// ---------------- LDS-staged double-buffered MFMA GEMM ----------------
template <int KF>
__global__ __launch_bounds__(256) void gemm_lds(
    const unsigned short* __restrict__ A, const unsigned short* __restrict__ Bt,
    const float* __restrict__ biasL, const float* __restrict__ biasR, int NL,
    unsigned short* __restrict__ C, int M, int nrb, int N)
{
    __shared__ unsigned short lds[2][16 * 512];   // 2 x 16KB
    int wid = threadIdx.x >> 6, lane = threadIdx.x & 63;
    int wm = wid >> 1, wn = wid & 1;
    int rb0 = blockIdx.x * 8;
    int cb0 = blockIdx.y * 8;

    auto stage = [&](int buf, int kf) {
#pragma unroll
        for (int i = 0; i < 4; i++) {
            int c = wid * 4 + i;
            const unsigned short* src;
            if (c < 8) {
                int rb = rb0 + c;
                rb = rb < nrb ? rb : nrb - 1;
                src = A + ((size_t)rb * KF + kf) * 512;
            } else {
                src = Bt + ((size_t)(cb0 + c - 8) * KF + kf) * 512;
            }
            GLL(src + lane * 8, &lds[buf][c * 512]);
        }
    };

    f32x4 acc[4][4] = {};
    stage(0, 0);
    __syncthreads();
    int cur = 0;
    for (int kf = 0; kf < KF; kf++) {
        if (kf + 1 < KF) stage(cur ^ 1, kf + 1);
        bf16x8 a[4], b[4];
#pragma unroll
        for (int r = 0; r < 4; r++)
            a[r] = *(const bf16x8*)&lds[cur][(wm * 4 + r) * 512 + lane * 8];
#pragma unroll
        for (int j = 0; j < 4; j++)
            b[j] = *(const bf16x8*)&lds[cur][(8 + wn * 4 + j) * 512 + lane * 8];
#pragma unroll
        for (int j = 0; j < 4; j++)
#pragma unroll
            for (int r = 0; r < 4; r++)
                acc[r][j] = MFMA(a[r], b[j], acc[r][j], 0, 0, 0);
        __syncthreads();
        cur ^= 1;
    }

    int ccol = lane & 15, crow = (lane >> 4) * 4;
#pragma unroll
    for (int r = 0; r < 4; r++) {
#pragma unroll
        for (int j = 0; j < 4; j++) {
            int col = (cb0 + wn * 4 + j) * 16 + ccol;
            float bv = (col < NL) ? biasL[col] : biasR[col - NL];
#pragma unroll
            for (int q = 0; q < 4; q++) {
                int row = (rb0 + wm * 4 + r) * 16 + crow + q;
                if (row < M) C[(size_t)row * N + col] = f2bf(acc[r][j][q] + bv);
            }
        }
    }
}

// ---------------- CSR build (single atomic pass) ----------------
__global__ void hist_dst_pos(const int* __restrict__ eidx, const int* __restrict__ flagp,
                             int E, int n, int* __restrict__ cnt, int* __restrict__ pos)
{
    int t = blockIdx.x * blockDim.x + threadIdx.x;
    if (t >= E + n) return;
    int is64 = *flagp;
    int d = (t < E) ? ld_idx(eidx, E + t, is64) : (t - E);
    pos[t] = atomicAdd(&cnt[d], 1);
}

__global__ __launch_bounds__(1024) void scan1(const int* __restrict__ cnt,
                                              int* __restrict__ rowptr, int* __restrict__ psum, int n)
{
    __shared__ int wsum[16];
    int tid = threadIdx.x, lane = tid & 63, w = tid >> 6;
    int gid = blockIdx.x * 1024 + tid;
    int v = (gid < n) ? cnt[gid] : 0;
    int sc = v;
#pragma unroll
    for (int o = 1; o < 64; o <<= 1) { int t2 = __shfl_up(sc, o); if (lane >= o) sc += t2; }
    if (lane == 63) wsum[w] = sc;
    __syncthreads();
    if (tid < 16) {
        int t2 = wsum[tid];
#pragma unroll
        for (int o = 1; o < 16; o <<= 1) { int u = __shfl_up(t2, o); if (tid >= o) t2 += u; }
        wsum[tid] = t2;
    }
    __syncthreads();
    int wofs = w ? wsum[w - 1] : 0;
    if (gid < n) rowptr[gid] = wofs + sc - v;
    if (tid == 1023) psum[blockIdx.x] = wsum[15];
}

__global__ void scan2(const int* __restrict__ psum, int* __restrict__ pofs,
                      int* __restrict__ rowptr_n, int nb)
{
    int lane = threadIdx.x;
    int v = (lane < nb) ? psum[lane] : 0;
    int sc = v;
#pragma unroll
    for (int o = 1; o < 64; o <<= 1) { int t = __shfl_up(sc, o); if (lane >= o) sc += t; }
    if (lane < nb) pofs[lane] = sc - v;
    if (lane == 63) *rowptr_n = sc;
}

__global__ __launch_bounds__(1024) void scan3(int* __restrict__ rowptr,
                                              const int* __restrict__ pofs, int n)
{
    int gid = blockIdx.x * 1024 + threadIdx.x;
    if (gid < n) rowptr[gid] += pofs[blockIdx.x];
}

__global__ void scatter_pos(const int* __restrict__ eidx, const int* __restrict__ flagp,
                            int E, int n, const int* __restrict__ rowptr,
                            const int* __restrict__ pos, int* __restrict__ sord)
{
    int t = blockIdx.x * blockDim.x + threadIdx.x;
    if (t >= E + n) return;
    int is64 = *flagp;
    int s, d;
    if (t < E) { s = ld_idx(eidx, t, is64); d = ld_idx(eidx, E + t, is64); }
    else { s = t - E; d = s; }
    sord[rowptr[d] + pos[t]] = s;
}

// ---------------- fused edge phase, H=4: one WAVE per node, 8ch/lane, 2 slots x 2 unroll ----
// lane: slot = lane>>5 (edge), sub = lane&31, channel base off = sub*8 (covers 256 ch).
// no-max softmax; score folds LOG2E+lrelu split into a6/a4. 4 gathers in flight/step.
__global__ __launch_bounds__(64) void node_attn_h4(
    const unsigned short* __restrict__ xlr,  // [n][512]: 0-255 xl, 256-511 xr
    const float* __restrict__ att, const float* __restrict__ bias,
    const int* __restrict__ rowptr, const int* __restrict__ sord, int n,
    unsigned short* __restrict__ outb)       // frag layout (feeds gemm2)
{
    int d = blockIdx.x;
    int lane = threadIdx.x;
    int slot = lane >> 5, sub = lane & 31;
    int off = sub * 8;
    float xr8[8], a68[8], a48[8];
    {
        uint4 u = *(const uint4*)(xlr + (size_t)d * 512 + 256 + off);
        UNPK8(xr8, u);
        float4 av0 = *(const float4*)(att + off);
        float4 av1 = *(const float4*)(att + off + 4);
        float av[8] = {av0.x, av0.y, av0.z, av0.w, av1.x, av1.y, av1.z, av1.w};
#pragma unroll
        for (int c = 0; c < 8; c++) {
            a68[c] = av[c] * (0.6f * LOG2E);
            a48[c] = av[c] * (0.4f * LOG2E);
        }
    }
    int beg = rowptr[d], end = rowptr[d + 1];
    float ssum = 0.f;
    float o8[8] = {};
    for (int i = beg; i < end; i += 4) {
        int ia = i + slot, ib = i + 2 + slot;
        int va = ia < end, vb = ib < end;
        int sa = sord[va ? ia : i];
        int sb = sord[vb ? ib : i];
        uint4 ua = *(const uint4*)(xlr + (size_t)sa * 512 + off);
        uint4 ub = *(const uint4*)(xlr + (size_t)sb * 512 + off);
        float xa[8], xb[8];
        UNPK8(xa, ua); UNPK8(xb, ub);
        float pa = 0.f, pb = 0.f;
#pragma unroll
        for (int c = 0; c < 8; c++) {
            float ta = xa[c] + xr8[c];
            float tb = xb[c] + xr8[c];
            pa = fmaf(ta, a68[c], pa); pa = fmaf(fabsf(ta), a48[c], pa);
            pb = fmaf(tb, a68[c], pb); pb = fmaf(fabsf(tb), a48[c], pb);
        }
        pa += __shfl_xor(pa, 1); pb += __shfl_xor(pb, 1);
        pa += __shfl_xor(pa, 2); pb += __shfl_xor(pb, 2);
        pa += __shfl_xor(pa, 4); pb += __shfl_xor(pb, 4);  // uniform per 8-lane head group
        pa = va ? pa : -1e30f;
        pb = vb ? pb : -1e30f;
        float eva = EXP2(pa), evb = EXP2(pb);
        ssum += eva + evb;
#pragma unroll
        for (int c = 0; c < 8; c++) {
            o8[c] = fmaf(eva, xa[c], o8[c]);
            o8[c] = fmaf(evb, xb[c], o8[c]);
        }
    }
    // merge the 2 edge slots
    ssum += __shfl_xor(ssum, 32);
#pragma unroll
    for (int c = 0; c < 8; c++) o8[c] += __shfl_xor(o8[c], 32);
    if (slot == 0) {
        float inv = 1.f / (ssum + 1e-16f);
        float4 bv0 = *(const float4*)(bias + off);
        float4 bv1 = *(const float4*)(bias + off + 4);
        float bv[8] = {bv0.x, bv0.y, bv0.z, bv0.w, bv1.x, bv1.y, bv1.z, bv1.w};
        unsigned short r[8];
#pragma unroll
        for (int c = 0; c < 8; c++) {
            float v = o8[c] * inv + bv[c];
            v = fmaxf(v, 0.01f * v);
            r[c] = f2bf(v);
        }
        // frag store: row=d, channels off..off+7 = one full 8-elem chunk slot
        int rowblk = d >> 4, r16d = d & 15;
        int kf = off >> 5, kg = (off >> 3) & 3;
        size_t flat = (((size_t)rowblk * 8 + kf) * 64 + kg * 16 + r16d) * 8;
        ushort4 q0 = {r[0], r[1], r[2], r[3]}, q1 = {r[4], r[5], r[6], r[7]};
        *(ushort4*)(outb + flat) = q0;
        *(ushort4*)(outb + flat + 4) = q1;
    }
}

// ---------------- fused edge phase, H=1: one WAVE per node, 8ch/lane, 8 slots x 2 unroll ----
__global__ __launch_bounds__(64) void node_attn_h1(
    const unsigned short* __restrict__ xlr,  // [n][128]: 0-63 xl, 64-127 xr
    const float* __restrict__ att, const float* __restrict__ bias,
    const int* __restrict__ rowptr, const int* __restrict__ sord, int n,
    float* __restrict__ outf)
{
    int d = blockIdx.x;
    int lane = threadIdx.x;
    int slot = lane >> 3, sub = lane & 7;
    int off = sub * 8;
    float xr8[8], a68[8], a48[8];
    {
        uint4 u = *(const uint4*)(xlr + (size_t)d * 128 + 64 + off);
        UNPK8(xr8, u);
        float4 av0 = *(const float4*)(att + off);
        float4 av1 = *(const float4*)(att + off + 4);
        float av[8] = {av0.x, av0.y, av0.z, av0.w, av1.x, av1.y, av1.z, av1.w};
#pragma unroll
        for (int c = 0; c < 8; c++) {
            a68[c] = av[c] * (0.6f * LOG2E);
            a48[c] = av[c] * (0.4f * LOG2E);
        }
    }
    int beg = rowptr[d], end = rowptr[d + 1];
    float ssum = 0.f;
    float o8[8] = {};
    for (int i = beg; i < end; i += 16) {
        int ia = i + slot, ib = i + 8 + slot;
        int va = ia < end, vb = ib < end;
        int sa = sord[va ? ia : i];
        int sb = sord[vb ? ib : i];
        uint4 ua = *(const uint4*)(xlr + (size_t)sa * 128 + off);
        uint4 ub = *(const uint4*)(xlr + (size_t)sb * 128 + off);
        float xa[8], xb[8];
        UNPK8(xa, ua); UNPK8(xb, ub);
        float pa = 0.f, pb = 0.f;
#pragma unroll
        for (int c = 0; c < 8; c++) {
            float ta = xa[c] + xr8[c];
            float tb = xb[c] + xr8[c];
            pa = fmaf(ta, a68[c], pa); pa = fmaf(fabsf(ta), a48[c], pa);
            pb = fmaf(tb, a68[c], pb); pb = fmaf(fabsf(tb), a48[c], pb);
        }
        pa += __shfl_xor(pa, 1); pb += __shfl_xor(pb, 1);
        pa += __shfl_xor(pa, 2); pb += __shfl_xor(pb, 2);
        pa += __shfl_xor(pa, 4); pb += __shfl_xor(pb, 4);  // uniform per 8-lane edge group
        pa = va ? pa : -1e30f;
        pb = vb ? pb : -1e30f;
        float eva = EXP2(pa), evb = EXP2(pb);
        ssum += eva + evb;
#pragma unroll
        for (int c = 0; c < 8; c++) {
            o8[c] = fmaf(eva, xa[c], o8[c]);
            o8[c] = fmaf(evb, xb[c], o8[c]);
        }
    }
    // merge the 8 edge slots
#pragma unroll
    for (int offs = 8; offs <= 32; offs <<= 1) {
        ssum += __shfl_xor(ssum, offs);
#pragma unroll
        for (int c = 0; c < 8; c++) o8[c] += __shfl_xor(o8[c], offs);
    }
    if (slot == 0) {
        float inv = 1.f / (ssum + 1e-16f);
        float4 bv0 = *(const float4*)(bias + off);
        float4 bv1 = *(const float4*)(bias + off + 4);
        float4 res0, res1;
        res0.x = o8[0] * inv + bv0.x; res0.y = o8[1] * inv + bv0.y;
        res0.z = o8[2] * inv + bv0.z; res0.w = o8[3] * inv + bv0.w;
        res1.x = o8[4] * inv + bv1.x; res1.y = o8[5] * inv + bv1.y;
        res1.z = o8[6] * inv + bv1.z; res1.w = o8[7] * inv + bv1.w;
        *(float4*)(outf + (size_t)d * 64 + off) = res0;
        *(float4*)(outf + (size_t)d * 64 + off + 4) = res1;
    }
}

// fused predict head
__global__ void predict_head(const float* __restrict__ h2,
                             const float* __restrict__ Wp1, const float* __restrict__ bp1,
                             const float* __restrict__ Wp2, const float* __restrict__ bp2,
                             float* __restrict__ logits, int n)
{
    int i = blockIdx.x * blockDim.x + threadIdx.x;
    if (i >= n) return;
    float h[64];
#pragma unroll
    for (int c = 0; c < 64; c++) h[c] = h2[(long long)i * 64 + c];
    float logit = bp2[0];
#pragma unroll
    for (int j = 0; j < 32; j++) {
        float z = bp1[j];
#pragma unroll
        for (int c = 0; c < 64; c++) z += h[c] * Wp1[c * 32 + j];
        z = lrelu(z, 0.01f);
        logit += z * Wp2[j];
    }
    logits[i] = logit;
}

extern "C" void kernel_launch(void* const* d_in, const int* in_sizes, int n_in,
                              void* d_out, int out_size, void* d_ws, size_t ws_size,
                              hipStream_t stream)
{
    const float* x    = (const float*)d_in[0];
    const int*   eidx = (const int*)d_in[1];
    const float* W1l  = (const float*)d_in[2];
    const float* b1l  = (const float*)d_in[3];
    const float* W1r  = (const float*)d_in[4];
    const float* b1r  = (const float*)d_in[5];
    const float* att1 = (const float*)d_in[6];
    const float* bias1= (const float*)d_in[7];
    const float* W2l  = (const float*)d_in[8];
    const float* b2l  = (const float*)d_in[9];
    const float* W2r  = (const float*)d_in[10];
    const float* b2r  = (const float*)d_in[11];
    const float* att2 = (const float*)d_in[12];
    const float* bias2= (const float*)d_in[13];
    const float* Wp1  = (const float*)d_in[14];
    const float* bp1  = (const float*)d_in[15];
    const float* Wp2  = (const float*)d_in[16];
    const float* bp2  = (const float*)d_in[17];

    const int n = in_sizes[0] / 256;  // 50000
    const int E = in_sizes[1] / 2;    // 600000
    const int Etot = E + n;
    const int nb = (n + 1023) / 1024;
    const int nrb = (n + 15) / 16;    // 16-row blocks

    float* out = (float*)d_out;       // [0,n): logits ; [n, n+n*64): h
    unsigned short* ws16 = (unsigned short*)d_ws;

    // workspace layout (shorts)
    unsigned short* xb    = ws16;                         // nrb*4096 (frag; aliased h1b)
    unsigned short* xlr1  = xb + (size_t)nrb * 4096;      // n*512 row-major (aliased xlr2)
    unsigned short* w1t   = xlr1 + (size_t)n * 512;       // 131072 (frag)
    unsigned short* w2t   = w1t + 131072;                 // 32768 (frag)
    int*            rowptr= (int*)(w2t + 32768);          // n+1
    int*            cnt   = rowptr + (n + 1);             // n
    int*            sord  = cnt + n;                      // Etot
    int*            pos   = sord + Etot;                  // Etot
    int*            psum  = pos + Etot;                   // 64
    int*            pofs  = psum + 64;                    // 64
    int*            flagp = pofs + 64;                    // 1
    unsigned short* h1b   = xb;                           // attn1 out (frag), gemm2 in
    unsigned short* xlr2  = xlr1;                         // n*128 row-major
    float*          h2    = out + n;

    detect_i64<<<1, 64, 0, stream>>>((const unsigned int*)eidx, flagp);

    // ---- CSR build (one atomic pass) ----
    hipMemsetAsync(cnt, 0, (size_t)n * sizeof(int), stream);
    hist_dst_pos<<<(Etot + 255) / 256, 256, 0, stream>>>(eidx, flagp, E, n, cnt, pos);
    scan1<<<nb, 1024, 0, stream>>>(cnt, rowptr, psum, n);
    scan2<<<1, 64, 0, stream>>>(psum, pofs, rowptr + n, nb);
    scan3<<<nb, 1024, 0, stream>>>(rowptr, pofs, n);
    scatter_pos<<<(Etot + 255) / 256, 256, 0, stream>>>(eidx, flagp, E, n, rowptr, pos, sord);

    // ---- conversions (frag layouts, single launch) ----
    convert_all<<<(nrb * 512 + 20480 + 255) / 256, 256, 0, stream>>>(
        x, W1l, W1r, W2l, W2r, xb, w1t, w2t, n, nrb);

    // ---- layer 1 projection: [n,256] @ [512,256]^T, LDS-staged 128x128 tiles ----
    {
        dim3 grid((nrb + 7) / 8, 4);
        gemm_lds<8><<<grid, 256, 0, stream>>>(xb, w1t, b1l, b1r, 256, xlr1, n, nrb, 512);
    }

    // ---- layer 1 edge phase (one wave per node, 4 gathers in flight) ----
    node_attn_h4<<<n, 64, 0, stream>>>(xlr1, att1, bias1, rowptr, sord, n, h1b);

    // ---- layer 2 projection: [n,256] @ [128,256]^T ----
    {
        dim3 grid((nrb + 7) / 8, 1);
        gemm_lds<8><<<grid, 256, 0, stream>>>(h1b, w2t, b2l, b2r, 64, xlr2, n, nrb, 128);
    }

    // ---- layer 2 edge phase (one wave per node, 2x unroll) ----
    node_attn_h1<<<n, 64, 0, stream>>>(xlr2, att2, bias2, rowptr, sord, n, h2);

    // ---- predict head ----
    predict_head<<<(n + 255) / 256, 256, 0, stream>>>(h2, Wp1, bp1, Wp2, bp2, out, n);
}

// Round 17
// 226.758 us; speedup vs baseline: 1.0417x; 1.0298x over previous
//
#include <hip/hip_runtime.h>

typedef __attribute__((ext_vector_type(8))) __bf16 bf16x8;
typedef __attribute__((ext_vector_type(4))) float f32x4;

#define EXP2 __builtin_amdgcn_exp2f
#define LOG2E 1.44269504f
#define MFMA __builtin_amdgcn_mfma_f32_16x16x32_bf16

// async global->LDS 16B per lane: dst wave-uniform, src per-lane (+lane*16B)
#define GLL(srcp, dstp) __builtin_amdgcn_global_load_lds( \
    (const __attribute__((address_space(1))) void*)(srcp), \
    (__attribute__((address_space(3))) void*)(dstp), 16, 0, 0)

__device__ __forceinline__ float lrelu(float v, float s) { return v > 0.f ? v : v * s; }

__device__ __forceinline__ unsigned short f2bf(float f) {
    unsigned int u = __float_as_uint(f);
    u += 0x7FFFu + ((u >> 16) & 1u);
    return (unsigned short)(u >> 16);
}
__device__ __forceinline__ float bf2f(unsigned short u) {
    return __uint_as_float((unsigned int)u << 16);
}

__device__ __forceinline__ int ld_idx(const int* p, int e, int is64) {
    return is64 ? (int)(((const long long*)p)[e]) : p[e];
}

__global__ void detect_i64(const unsigned int* idx, int* flag) {
    if (blockIdx.x == 0 && threadIdx.x == 0) {
        int all0 = 1;
        for (int i = 1; i < 256; i += 2) {
            if (idx[i] != 0u) { all0 = 0; break; }
        }
        *flag = all0;
    }
}

// ---------------- fused conversions (fragment-linear layouts) ----------------
__global__ void convert_all(const float* __restrict__ x,
                            const float* __restrict__ W1l, const float* __restrict__ W1r,
                            const float* __restrict__ W2l, const float* __restrict__ W2r,
                            unsigned short* __restrict__ xb,
                            unsigned short* __restrict__ w1t, unsigned short* __restrict__ w2t,
                            int n, int nrb)
{
    int t = blockIdx.x * blockDim.x + threadIdx.x;
    int A = nrb * 512;
    if (t < A) {
        int lane = t & 63;
        int kf = (t >> 6) & 7;
        int rowblk = t >> 9;
        int r16 = lane & 15, kg = lane >> 4;
        int row = rowblk * 16 + r16;
        int k0 = kf * 32 + kg * 8;
        ushort4 o0 = {0, 0, 0, 0}, o1 = {0, 0, 0, 0};
        if (row < n) {
            float4 v0 = *(const float4*)(x + (size_t)row * 256 + k0);
            float4 v1 = *(const float4*)(x + (size_t)row * 256 + k0 + 4);
            o0.x = f2bf(v0.x); o0.y = f2bf(v0.y); o0.z = f2bf(v0.z); o0.w = f2bf(v0.w);
            o1.x = f2bf(v1.x); o1.y = f2bf(v1.y); o1.z = f2bf(v1.z); o1.w = f2bf(v1.w);
        }
        *(ushort4*)(xb + (size_t)t * 8) = o0;
        *(ushort4*)(xb + (size_t)t * 8 + 4) = o1;
        return;
    }
    int tw = t - A;
    const float *Wl, *Wr;
    unsigned short* dst;
    int NL, base;
    if (tw < 16384)      { Wl = W1l; Wr = W1r; dst = w1t; NL = 256; base = tw; }
    else if (tw < 20480) { Wl = W2l; Wr = W2r; dst = w2t; NL = 64;  base = tw - 16384; }
    else return;
    int lane = base & 63, kf = (base >> 6) & 7, colblk = base >> 9;
    int r16 = lane & 15, kg = lane >> 4;
    int col = colblk * 16 + r16;
    int k0 = kf * 32 + kg * 8;
    const float* W = (col < NL) ? Wl : Wr;
    int c = (col < NL) ? col : col - NL;
    unsigned short v[8];
#pragma unroll
    for (int e = 0; e < 8; e++) v[e] = f2bf(W[(size_t)(k0 + e) * NL + c]);
    ushort4 o0 = {v[0], v[1], v[2], v[3]}, o1 = {v[4], v[5], v[6], v[7]};
    *(ushort4*)(dst + (size_t)base * 8) = o0;
    *(ushort4*)(dst + (size_t)base * 8 + 4) = o1;
}

// ---------------- LDS-staged double-buffered MFMA GEMM ----------------
template <int KF>
__global__ __launch_bounds__(256) void gemm_lds(
    const unsigned short* __restrict__ A, const unsigned short* __restrict__ Bt,
    const float* __restrict__ biasL, const float* __restrict__ biasR, int NL,
    unsigned short* __restrict__ C, int M, int nrb, int N)
{
    __shared__ unsigned short lds[2][16 * 512];   // 2 x 16KB
    int wid = threadIdx.x >> 6, lane = threadIdx.x & 63;
    int wm = wid >> 1, wn = wid & 1;
    int rb0 = blockIdx.x * 8;
    int cb0 = blockIdx.y * 8;

    auto stage = [&](int buf, int kf) {
#pragma unroll
        for (int i = 0; i < 4; i++) {
            int c = wid * 4 + i;
            const unsigned short* src;
            if (c < 8) {
                int rb = rb0 + c;
                rb = rb < nrb ? rb : nrb - 1;
                src = A + ((size_t)rb * KF + kf) * 512;
            } else {
                src = Bt + ((size_t)(cb0 + c - 8) * KF + kf) * 512;
            }
            GLL(src + lane * 8, &lds[buf][c * 512]);
        }
    };

    f32x4 acc[4][4] = {};
    stage(0, 0);
    __syncthreads();
    int cur = 0;
    for (int kf = 0; kf < KF; kf++) {
        if (kf + 1 < KF) stage(cur ^ 1, kf + 1);
        bf16x8 a[4], b[4];
#pragma unroll
        for (int r = 0; r < 4; r++)
            a[r] = *(const bf16x8*)&lds[cur][(wm * 4 + r) * 512 + lane * 8];
#pragma unroll
        for (int j = 0; j < 4; j++)
            b[j] = *(const bf16x8*)&lds[cur][(8 + wn * 4 + j) * 512 + lane * 8];
#pragma unroll
        for (int j = 0; j < 4; j++)
#pragma unroll
            for (int r = 0; r < 4; r++)
                acc[r][j] = MFMA(a[r], b[j], acc[r][j], 0, 0, 0);
        __syncthreads();
        cur ^= 1;
    }

    int ccol = lane & 15, crow = (lane >> 4) * 4;
#pragma unroll
    for (int r = 0; r < 4; r++) {
#pragma unroll
        for (int j = 0; j < 4; j++) {
            int col = (cb0 + wn * 4 + j) * 16 + ccol;
            float bv = (col < NL) ? biasL[col] : biasR[col - NL];
#pragma unroll
            for (int q = 0; q < 4; q++) {
                int row = (rb0 + wm * 4 + r) * 16 + crow + q;
                if (row < M) C[(size_t)row * N + col] = f2bf(acc[r][j][q] + bv);
            }
        }
    }
}

// ---------------- CSR build (single atomic pass) ----------------
__global__ void hist_dst_pos(const int* __restrict__ eidx, const int* __restrict__ flagp,
                             int E, int n, int* __restrict__ cnt, int* __restrict__ pos)
{
    int t = blockIdx.x * blockDim.x + threadIdx.x;
    if (t >= E + n) return;
    int is64 = *flagp;
    int d = (t < E) ? ld_idx(eidx, E + t, is64) : (t - E);
    pos[t] = atomicAdd(&cnt[d], 1);
}

__global__ __launch_bounds__(1024) void scan1(const int* __restrict__ cnt,
                                              int* __restrict__ rowptr, int* __restrict__ psum, int n)
{
    __shared__ int wsum[16];
    int tid = threadIdx.x, lane = tid & 63, w = tid >> 6;
    int gid = blockIdx.x * 1024 + tid;
    int v = (gid < n) ? cnt[gid] : 0;
    int sc = v;
#pragma unroll
    for (int o = 1; o < 64; o <<= 1) { int t2 = __shfl_up(sc, o); if (lane >= o) sc += t2; }
    if (lane == 63) wsum[w] = sc;
    __syncthreads();
    if (tid < 16) {
        int t2 = wsum[tid];
#pragma unroll
        for (int o = 1; o < 16; o <<= 1) { int u = __shfl_up(t2, o); if (tid >= o) t2 += u; }
        wsum[tid] = t2;
    }
    __syncthreads();
    int wofs = w ? wsum[w - 1] : 0;
    if (gid < n) rowptr[gid] = wofs + sc - v;
    if (tid == 1023) psum[blockIdx.x] = wsum[15];
}

__global__ void scan2(const int* __restrict__ psum, int* __restrict__ pofs,
                      int* __restrict__ rowptr_n, int nb)
{
    int lane = threadIdx.x;
    int v = (lane < nb) ? psum[lane] : 0;
    int sc = v;
#pragma unroll
    for (int o = 1; o < 64; o <<= 1) { int t = __shfl_up(sc, o); if (lane >= o) sc += t; }
    if (lane < nb) pofs[lane] = sc - v;
    if (lane == 63) *rowptr_n = sc;
}

__global__ __launch_bounds__(1024) void scan3(int* __restrict__ rowptr,
                                              const int* __restrict__ pofs, int n)
{
    int gid = blockIdx.x * 1024 + threadIdx.x;
    if (gid < n) rowptr[gid] += pofs[blockIdx.x];
}

__global__ void scatter_pos(const int* __restrict__ eidx, const int* __restrict__ flagp,
                            int E, int n, const int* __restrict__ rowptr,
                            const int* __restrict__ pos, int* __restrict__ sord)
{
    int t = blockIdx.x * blockDim.x + threadIdx.x;
    if (t >= E + n) return;
    int is64 = *flagp;
    int s, d;
    if (t < E) { s = ld_idx(eidx, t, is64); d = ld_idx(eidx, E + t, is64); }
    else { s = t - E; d = s; }
    sord[rowptr[d] + pos[t]] = s;
}

// ---------------- fused edge phase (no-max softmax: shift-invariant, scores |p|<~20) ----------------
// score via lrelu(t)*att = t*(0.6*att) + |t|*(0.4*att), LOG2E folded into att
#define SCOREX(p, xv) { float t_; p = 0.f;                              \
    t_ = xv.x + xrv.x; p = fmaf(t_, a6.x, p); p = fmaf(fabsf(t_), a4.x, p); \
    t_ = xv.y + xrv.y; p = fmaf(t_, a6.y, p); p = fmaf(fabsf(t_), a4.y, p); \
    t_ = xv.z + xrv.z; p = fmaf(t_, a6.z, p); p = fmaf(fabsf(t_), a4.z, p); \
    t_ = xv.w + xrv.w; p = fmaf(t_, a6.w, p); p = fmaf(fabsf(t_), a4.w, p); }

#define RED16(p) { p += __shfl_xor(p, 1); p += __shfl_xor(p, 2);    \
                   p += __shfl_xor(p, 4); p += __shfl_xor(p, 8); }

#define EACC(v, xv) { float ev = EXP2(v); ssum += ev;                \
    o.x = fmaf(ev, xv.x, o.x); o.y = fmaf(ev, xv.y, o.y);            \
    o.z = fmaf(ev, xv.z, o.z); o.w = fmaf(ev, xv.w, o.w); }

#define CVT4(f, u) float4 f = { bf2f(u.x), bf2f(u.y), bf2f(u.z), bf2f(u.w) };

__global__ __launch_bounds__(256) void node_attn_h4(
    const unsigned short* __restrict__ xlr,  // [n][512] row-major
    const float* __restrict__ att, const float* __restrict__ bias,
    const int* __restrict__ rowptr, const int* __restrict__ sord, int n,
    unsigned short* __restrict__ outb)       // frag layout (feeds gemm2)
{
    int d = (blockIdx.x * blockDim.x + threadIdx.x) >> 6;
    int lane = threadIdx.x & 63;
    if (d >= n) return;
    int off = (lane >> 4) * 64 + (lane & 15) * 4;  // h*64 + c0
    ushort4 xru = *(const ushort4*)(xlr + (size_t)d * 512 + 256 + off);
    CVT4(xrv, xru);
    float4 atv = *(const float4*)(att + off);
    float4 a6, a4;
    a6.x = atv.x * (0.6f * LOG2E); a6.y = atv.y * (0.6f * LOG2E);
    a6.z = atv.z * (0.6f * LOG2E); a6.w = atv.w * (0.6f * LOG2E);
    a4.x = atv.x * (0.4f * LOG2E); a4.y = atv.y * (0.4f * LOG2E);
    a4.z = atv.z * (0.4f * LOG2E); a4.w = atv.w * (0.4f * LOG2E);
    int beg = rowptr[d], end = rowptr[d + 1];
    float ssum = 0.f;
    float4 o = {0.f, 0.f, 0.f, 0.f};
    for (int i = beg; i < end; i += 4) {
        int i1 = i + 1, i2 = i + 2, i3 = i + 3;
        int v1 = i1 < end, v2 = i2 < end, v3 = i3 < end;
        int s0 = sord[i];
        int s1 = sord[v1 ? i1 : i];
        int s2 = sord[v2 ? i2 : i];
        int s3 = sord[v3 ? i3 : i];
        ushort4 u0 = *(const ushort4*)(xlr + (size_t)s0 * 512 + off);
        ushort4 u1 = *(const ushort4*)(xlr + (size_t)s1 * 512 + off);
        ushort4 u2 = *(const ushort4*)(xlr + (size_t)s2 * 512 + off);
        ushort4 u3 = *(const ushort4*)(xlr + (size_t)s3 * 512 + off);
        CVT4(x0, u0); CVT4(x1, u1); CVT4(x2, u2); CVT4(x3, u3);
        float p0, p1, p2, p3;
        SCOREX(p0, x0); SCOREX(p1, x1); SCOREX(p2, x2); SCOREX(p3, x3);
        RED16(p0); RED16(p1); RED16(p2); RED16(p3);
        p1 = v1 ? p1 : -1e30f;
        p2 = v2 ? p2 : -1e30f;
        p3 = v3 ? p3 : -1e30f;
        EACC(p0, x0); EACC(p1, x1); EACC(p2, x2); EACC(p3, x3);
    }
    float inv = 1.f / (ssum + 1e-16f);
    float4 bv = *(const float4*)(bias + off);
    float r0 = o.x * inv + bv.x, r1 = o.y * inv + bv.y;
    float r2 = o.z * inv + bv.z, r3 = o.w * inv + bv.w;
    r0 = fmaxf(r0, 0.01f * r0); r1 = fmaxf(r1, 0.01f * r1);
    r2 = fmaxf(r2, 0.01f * r2); r3 = fmaxf(r3, 0.01f * r3);
    ushort4 ov;
    ov.x = f2bf(r0); ov.y = f2bf(r1); ov.z = f2bf(r2); ov.w = f2bf(r3);
    // store in frag layout: row=d, cols off..off+3
    int rowblk = d >> 4, r16d = d & 15;
    int kf = off >> 5, kg2 = (off >> 3) & 3, e0 = off & 7;
    size_t flat = (((size_t)rowblk * 8 + kf) * 64 + kg2 * 16 + r16d) * 8 + e0;
    *(ushort4*)(outb + flat) = ov;
}

// ---------------- fused edge phase, H=1 (no-max) ----------------
__global__ __launch_bounds__(256) void node_attn_h1(
    const unsigned short* __restrict__ xlr,  // [n][128] row-major
    const float* __restrict__ att, const float* __restrict__ bias,
    const int* __restrict__ rowptr, const int* __restrict__ sord, int n,
    float* __restrict__ outf)
{
    int d = (blockIdx.x * blockDim.x + threadIdx.x) >> 6;
    int lane = threadIdx.x & 63;
    if (d >= n) return;
    int sg = lane >> 4, c0 = (lane & 15) * 4;
    ushort4 xru = *(const ushort4*)(xlr + (size_t)d * 128 + 64 + c0);
    CVT4(xrv, xru);
    float4 atv = *(const float4*)(att + c0);
    float4 a6, a4;
    a6.x = atv.x * (0.6f * LOG2E); a6.y = atv.y * (0.6f * LOG2E);
    a6.z = atv.z * (0.6f * LOG2E); a6.w = atv.w * (0.6f * LOG2E);
    a4.x = atv.x * (0.4f * LOG2E); a4.y = atv.y * (0.4f * LOG2E);
    a4.z = atv.z * (0.4f * LOG2E); a4.w = atv.w * (0.4f * LOG2E);
    int beg = rowptr[d], end = rowptr[d + 1];
    float ssum = 0.f;
    float4 o = {0.f, 0.f, 0.f, 0.f};
    for (int i0 = beg; i0 < end; i0 += 8) {
        int ia = i0 + sg, ib = i0 + 4 + sg;
        int va = ia < end, vb = ib < end;
        int sa = sord[va ? ia : beg];
        int sb = sord[vb ? ib : beg];
        ushort4 ua = *(const ushort4*)(xlr + (size_t)sa * 128 + c0);
        ushort4 ub = *(const ushort4*)(xlr + (size_t)sb * 128 + c0);
        CVT4(xa, ua); CVT4(xb, ub);
        float pa, pb;
        SCOREX(pa, xa); SCOREX(pb, xb);
        RED16(pa); RED16(pb);
        pa = va ? pa : -1e30f;
        pb = vb ? pb : -1e30f;
        EACC(pa, xa); EACC(pb, xb);
    }
    // plain-sum merge of the 4 subgroup states
#pragma unroll
    for (int offs = 16; offs <= 32; offs <<= 1) {
        ssum += __shfl_xor(ssum, offs);
        o.x += __shfl_xor(o.x, offs); o.y += __shfl_xor(o.y, offs);
        o.z += __shfl_xor(o.z, offs); o.w += __shfl_xor(o.w, offs);
    }
    if (sg == 0) {
        float inv = 1.f / (ssum + 1e-16f);
        float4 bv = *(const float4*)(bias + c0);
        float4 res;
        res.x = o.x * inv + bv.x; res.y = o.y * inv + bv.y;
        res.z = o.z * inv + bv.z; res.w = o.w * inv + bv.w;
        *(float4*)(outf + (size_t)d * 64 + c0) = res;
    }
}

// fused predict head
__global__ void predict_head(const float* __restrict__ h2,
                             const float* __restrict__ Wp1, const float* __restrict__ bp1,
                             const float* __restrict__ Wp2, const float* __restrict__ bp2,
                             float* __restrict__ logits, int n)
{
    int i = blockIdx.x * blockDim.x + threadIdx.x;
    if (i >= n) return;
    float h[64];
#pragma unroll
    for (int c = 0; c < 64; c++) h[c] = h2[(long long)i * 64 + c];
    float logit = bp2[0];
#pragma unroll
    for (int j = 0; j < 32; j++) {
        float z = bp1[j];
#pragma unroll
        for (int c = 0; c < 64; c++) z += h[c] * Wp1[c * 32 + j];
        z = lrelu(z, 0.01f);
        logit += z * Wp2[j];
    }
    logits[i] = logit;
}

extern "C" void kernel_launch(void* const* d_in, const int* in_sizes, int n_in,
                              void* d_out, int out_size, void* d_ws, size_t ws_size,
                              hipStream_t stream)
{
    const float* x    = (const float*)d_in[0];
    const int*   eidx = (const int*)d_in[1];
    const float* W1l  = (const float*)d_in[2];
    const float* b1l  = (const float*)d_in[3];
    const float* W1r  = (const float*)d_in[4];
    const float* b1r  = (const float*)d_in[5];
    const float* att1 = (const float*)d_in[6];
    const float* bias1= (const float*)d_in[7];
    const float* W2l  = (const float*)d_in[8];
    const float* b2l  = (const float*)d_in[9];
    const float* W2r  = (const float*)d_in[10];
    const float* b2r  = (const float*)d_in[11];
    const float* att2 = (const float*)d_in[12];
    const float* bias2= (const float*)d_in[13];
    const float* Wp1  = (const float*)d_in[14];
    const float* bp1  = (const float*)d_in[15];
    const float* Wp2  = (const float*)d_in[16];
    const float* bp2  = (const float*)d_in[17];

    const int n = in_sizes[0] / 256;  // 50000
    const int E = in_sizes[1] / 2;    // 600000
    const int Etot = E + n;
    const int nb = (n + 1023) / 1024;
    const int nrb = (n + 15) / 16;    // 16-row blocks

    float* out = (float*)d_out;       // [0,n): logits ; [n, n+n*64): h
    unsigned short* ws16 = (unsigned short*)d_ws;

    // workspace layout (shorts)
    unsigned short* xb    = ws16;                         // nrb*4096 (frag; aliased h1b)
    unsigned short* xlr1  = xb + (size_t)nrb * 4096;      // n*512 row-major (aliased xlr2)
    unsigned short* w1t   = xlr1 + (size_t)n * 512;       // 131072 (frag)
    unsigned short* w2t   = w1t + 131072;                 // 32768 (frag)
    int*            rowptr= (int*)(w2t + 32768);          // n+1
    int*            cnt   = rowptr + (n + 1);             // n
    int*            sord  = cnt + n;                      // Etot
    int*            pos   = sord + Etot;                  // Etot
    int*            psum  = pos + Etot;                   // 64
    int*            pofs  = psum + 64;                    // 64
    int*            flagp = pofs + 64;                    // 1
    unsigned short* h1b   = xb;                           // attn1 out (frag), gemm2 in
    unsigned short* xlr2  = xlr1;                         // n*128 row-major
    float*          h2    = out + n;

    detect_i64<<<1, 64, 0, stream>>>((const unsigned int*)eidx, flagp);

    // ---- CSR build (one atomic pass) ----
    hipMemsetAsync(cnt, 0, (size_t)n * sizeof(int), stream);
    hist_dst_pos<<<(Etot + 255) / 256, 256, 0, stream>>>(eidx, flagp, E, n, cnt, pos);
    scan1<<<nb, 1024, 0, stream>>>(cnt, rowptr, psum, n);
    scan2<<<1, 64, 0, stream>>>(psum, pofs, rowptr + n, nb);
    scan3<<<nb, 1024, 0, stream>>>(rowptr, pofs, n);
    scatter_pos<<<(Etot + 255) / 256, 256, 0, stream>>>(eidx, flagp, E, n, rowptr, pos, sord);

    // ---- conversions (frag layouts, single launch) ----
    convert_all<<<(nrb * 512 + 20480 + 255) / 256, 256, 0, stream>>>(
        x, W1l, W1r, W2l, W2r, xb, w1t, w2t, n, nrb);

    // ---- layer 1 projection: [n,256] @ [512,256]^T, LDS-staged 128x128 tiles ----
    {
        dim3 grid((nrb + 7) / 8, 4);
        gemm_lds<8><<<grid, 256, 0, stream>>>(xb, w1t, b1l, b1r, 256, xlr1, n, nrb, 512);
    }

    // ---- layer 1 edge phase ----
    node_attn_h4<<<(n + 3) / 4, 256, 0, stream>>>(xlr1, att1, bias1, rowptr, sord, n, h1b);

    // ---- layer 2 projection: [n,256] @ [128,256]^T ----
    {
        dim3 grid((nrb + 7) / 8, 1);
        gemm_lds<8><<<grid, 256, 0, stream>>>(h1b, w2t, b2l, b2r, 64, xlr2, n, nrb, 128);
    }

    // ---- layer 2 edge phase ----
    node_attn_h1<<<(n + 3) / 4, 256, 0, stream>>>(xlr2, att2, bias2, rowptr, sord, n, h2);

    // ---- predict head ----
    predict_head<<<(n + 255) / 256, 256, 0, stream>>>(h2, Wp1, bp1, Wp2, bp2, out, n);
}